// Round 10
// baseline (90.778 us; speedup 1.0000x reference)
//
#include <hip/hip_runtime.h>
#include <hip/hip_bf16.h>

#define B_N 32
#define T_N 512
#define D_N 512
#define H_N 512
#define M_N (B_N * T_N)   // 16384

typedef __attribute__((ext_vector_type(8))) short bf16x8;   // generic 16B
typedef __attribute__((ext_vector_type(4))) float f32x4;

__device__ __forceinline__ unsigned short f2bf(float f) {
  unsigned u = __float_as_uint(f);
  u += 0x7FFFu + ((u >> 16) & 1u);   // RTNE
  return (unsigned short)(u >> 16);
}
__device__ __forceinline__ unsigned short f2h(float f) {
  _Float16 h = (_Float16)f;
  return *(unsigned short*)&h;
}
__device__ __forceinline__ float h2f(unsigned short u) {
  _Float16 h = *(_Float16*)&u;
  return (float)h;
}

#define GLOAD16(g, l) __builtin_amdgcn_global_load_lds( \
    (const __attribute__((address_space(1))) void*)(g), \
    (__attribute__((address_space(3))) void*)(l), 16, 0, 0)

// ---------------------------------------------------------------------------
// prep: blocks [0,768) transpose+convert W -> Wt[id][n][k] bf16;
// blocks [768, 2816) convert x f32 -> bf16.
// ---------------------------------------------------------------------------
__global__ void prep_kernel(const float* __restrict__ x,
                            const float* __restrict__ W0,
                            const float* __restrict__ W1,
                            const float* __restrict__ W2,
                            unsigned short* __restrict__ xb,
                            unsigned short* __restrict__ Wt) {
  int blk = blockIdx.x;
  int tid = threadIdx.x;
  if (blk < 768) {
    __shared__ float tile[32][33];
    int id = blk >> 8;
    int t = blk & 255;
    int kr = (t >> 4) << 5;
    int nc = (t & 15) << 5;
    const float* W = (id == 0) ? W0 : (id == 1) ? W1 : W2;
    unsigned short* Wo = Wt + (size_t)id * (D_N * H_N);
    int tx = tid & 31, ty0 = tid >> 5;
    for (int ty = ty0; ty < 32; ty += 8)
      tile[ty][tx] = W[(size_t)(kr + ty) * H_N + nc + tx];
    __syncthreads();
    for (int ty = ty0; ty < 32; ty += 8)
      Wo[(size_t)(nc + ty) * D_N + kr + tx] = f2bf(tile[tx][ty]);
  } else {
    int b = blk - 768;
    const float4* xv = (const float4*)x;
#pragma unroll
    for (int u = 0; u < 4; ++u) {
      int i = b * 1024 + u * 256 + tid;
      float4 v = xv[i];
      ushort4 o;
      o.x = f2bf(v.x); o.y = f2bf(v.y); o.z = f2bf(v.z); o.w = f2bf(v.w);
      ((ushort4*)xb)[i] = o;
    }
  }
}

// zero the atomic row-sum accumulators (runs every call: deterministic)
__global__ void zero_sums(float* __restrict__ S) {
  ((float4*)S)[blockIdx.x * 256 + threadIdx.x] = (float4){0.f, 0.f, 0.f, 0.f};
}

// invert the row sums in place (IEEE divide; rcp-in-scan removed)
__global__ void inv_sums(float* __restrict__ S) {
  int i = blockIdx.x * 256 + threadIdx.x;   // 0..32767 covers S1+S2
  S[i] = 1.f / S[i];
}

// ---------------------------------------------------------------------------
// gemm3 v9: 128x128 tile, BK=32, 16 K-steps, 4 waves (64x64 quadrants).
// Triple-buffered LDS (3x16KB=48KB -> 3 blocks/CU) with raw s_barrier +
// counted vmcnt(4).  v8 lesson (absmax 7.3e-3): the schedule is correct in
// program order, but hipcc may move GLOAD16 / ds_read across inline-asm
// waitcnt despite the "memory" clobber (rule-18 class) -- so every
// wait+barrier is now sandwiched in __builtin_amdgcn_sched_barrier(0)
// fences, pinning {STAGE before the next wait} and {ds_reads after the
// barrier}.  Per thread per stage: 4 GLOAD16; at each wait outstanding=8,
// vmcnt(4) = previous stage complete; never 0 mid-loop (T4).
// BK=32: wave-wide ds_read_b128 covers 16 full 64B rows -> linear layout,
// zero conflicts (verified v8: SQ_LDS_BANK_CONFLICT=0).
// Epilogue: tanh/exp f16 + fused per-row exp-sums (shfl + atomicAdd).
// ---------------------------------------------------------------------------
__global__ __launch_bounds__(256) void gemm3(
    const unsigned short* __restrict__ xb,
    const unsigned short* __restrict__ Wt,
    const float* __restrict__ bDu,
    const float* __restrict__ bDr1,
    const float* __restrict__ bDr2,
    unsigned short* __restrict__ uP,
    unsigned short* __restrict__ e1P,
    unsigned short* __restrict__ e2P,
    float* __restrict__ S1,
    float* __restrict__ S2) {
  // A bufs @ 0/8192/16384, B bufs @ 24576/32768/40960 (each 128x32 bf16=8KB)
  __shared__ __align__(16) char smem[49152];

  const int tid = threadIdx.x;      // 0..255
  const int lane = tid & 63;
  const int wv = tid >> 6;          // 0..3
  const int wr = wv >> 1;           // wave row (0..1)
  const int wc = wv & 1;            // wave col (0..1)
  const int g = lane >> 4;          // 0..3 (16B slot in 64B row)
  const int c16 = lane & 15;

  const int m0 = blockIdx.x * 128;
  const int n0 = blockIdx.y * 128;
  const int id = blockIdx.z;
  const unsigned short* Wp = Wt + (size_t)id * (D_N * H_N);

  f32x4 acc[4][4];
#pragma unroll
  for (int mt = 0; mt < 4; ++mt)
#pragma unroll
    for (int nt = 0; nt < 4; ++nt)
      acc[mt][nt] = (f32x4){0.f, 0.f, 0.f, 0.f};

  // staging (linear): chunk c = i*256+tid -> row c>>2, slot c&3.
  const int srow = wv * 16 + (lane >> 2);           // + i*64
  const int selem = (lane & 3) * 8;                 // 16B slot in elems
  const unsigned short* aSrc = xb + (size_t)(m0 + srow) * D_N + selem;
  const unsigned short* bSrc = Wp + (size_t)(n0 + srow) * D_N + selem;
  const int dstOff = wv * 1024;                     // + i*4096 (+lane*16 hw)

#define STAGE(ab, kstep) do {                                            \
    const int k0_ = (kstep) * 32;                                        \
    GLOAD16(aSrc + k0_,                 smem + (ab) * 8192 + dstOff);    \
    GLOAD16(aSrc + 64 * D_N + k0_,      smem + (ab) * 8192 + dstOff + 4096); \
    GLOAD16(bSrc + k0_,         smem + 24576 + (ab) * 8192 + dstOff);    \
    GLOAD16(bSrc + 64 * D_N + k0_, smem + 24576 + (ab) * 8192 + dstOff + 4096); \
  } while (0)

#define COMPUTE(ab) do {                                                 \
    bf16x8 af[4], bb[4];                                                 \
    _Pragma("unroll")                                                    \
    for (int mt = 0; mt < 4; ++mt)                                       \
      af[mt] = *(const bf16x8*)(smem + (ab) * 8192 +                     \
                                (wr * 64 + mt * 16 + c16) * 64 + g * 16); \
    _Pragma("unroll")                                                    \
    for (int nt = 0; nt < 4; ++nt)                                       \
      bb[nt] = *(const bf16x8*)(smem + 24576 + (ab) * 8192 +             \
                                (wc * 64 + nt * 16 + c16) * 64 + g * 16); \
    _Pragma("unroll")                                                    \
    for (int mt = 0; mt < 4; ++mt)                                       \
      _Pragma("unroll")                                                  \
      for (int nt = 0; nt < 4; ++nt)                                     \
        acc[mt][nt] = __builtin_amdgcn_mfma_f32_16x16x32_bf16(           \
            af[mt], bb[nt], acc[mt][nt], 0, 0, 0);                       \
  } while (0)

  // wait+barrier pinned with sched_barrier(0) fences (rule-18 hardening):
  // nothing may be scheduled across -- STAGEs cannot sink past the wait,
  // ds_reads cannot hoist above the barrier.
#define WB(n) do {                                                       \
    __builtin_amdgcn_sched_barrier(0);                                   \
    asm volatile("s_waitcnt vmcnt(" #n ")\n\ts_barrier" ::: "memory");   \
    __builtin_amdgcn_sched_barrier(0);                                   \
  } while (0)

  STAGE(0, 0);
  STAGE(1, 1);
#pragma unroll 1
  for (int i = 0; i < 4; ++i) {      // t = 3i .. 3i+2 ; stages 3i+2 .. 3i+4
    WB(4); STAGE(2, 3 * i + 2); COMPUTE(0);
    WB(4); STAGE(0, 3 * i + 3); COMPUTE(1);
    WB(4); STAGE(1, 3 * i + 4); COMPUTE(2);
  }
  // tail: computes 12..15 (stages 14,15 still to issue)
  WB(4); STAGE(2, 14); COMPUTE(0);   // t=12
  WB(4); STAGE(0, 15); COMPUTE(1);   // t=13
  WB(4); COMPUTE(2);                 // t=14
  WB(0); COMPUTE(0);                 // t=15

  // ---- epilogue (elementwise + fused row-sums) ----
  const float* bp = (id == 0) ? bDu : (id == 1) ? bDr1 : bDr2;
  unsigned short* outp = (id == 0) ? uP : (id == 1) ? e1P : e2P;
  float* Sp = (id == 1) ? S1 : S2;
  float bias[4];
#pragma unroll
  for (int nt = 0; nt < 4; ++nt)
    bias[nt] = bp[n0 + wc * 64 + nt * 16 + c16];

#pragma unroll
  for (int mt = 0; mt < 4; ++mt)
#pragma unroll
    for (int i = 0; i < 4; ++i) {
      int row = m0 + wr * 64 + mt * 16 + g * 4 + i;
      unsigned short* op = outp + (size_t)row * H_N + n0 + wc * 64 + c16;
      if (id == 0) {
#pragma unroll
        for (int nt = 0; nt < 4; ++nt) {
          float z = acc[mt][nt][i] + bias[nt];
          float e = __expf(2.f * z);   // tanh(z) = 1 - 2/(e^{2z}+1)
          op[nt * 16] = f2h(1.f - 2.f * __builtin_amdgcn_rcpf(e + 1.f));
        }
      } else {
        float ps = 0.f;
#pragma unroll
        for (int nt = 0; nt < 4; ++nt) {
          float e = __expf(acc[mt][nt][i] + bias[nt]);
          op[nt * 16] = f2h(e);
          ps += e;
        }
        ps += __shfl_xor(ps, 1);
        ps += __shfl_xor(ps, 2);
        ps += __shfl_xor(ps, 4);
        ps += __shfl_xor(ps, 8);
        if (c16 == 0) atomicAdd(&Sp[row], ps);
      }
    }
#undef STAGE
#undef COMPUTE
#undef WB
}

// ---------------------------------------------------------------------------
// Chunked linear-recurrence scan: s_t = r1_t*s + r2_t*u_t, with
// r_i = e_i * iS_i (iS precomputed IEEE inverse; lane-uniform broadcast).
// ---------------------------------------------------------------------------
__global__ void scan_pass1(const unsigned short* __restrict__ e1P,
                           const unsigned short* __restrict__ e2P,
                           const unsigned short* __restrict__ uP,
                           const float* __restrict__ iS1,
                           const float* __restrict__ iS2,
                           float* __restrict__ cP,
                           float* __restrict__ cS) {
  int gt = blockIdx.x * 256 + threadIdx.x;  // 0..131071
  int chunk = gt >> 14;
  int r = gt & 16383;
  int b = r >> 9, h = r & 511;
  int row0 = b * T_N + chunk * 64;
  size_t idx = (size_t)row0 * H_N + h;
  float p = 1.f, s = 0.f;
#pragma unroll 4
  for (int j = 0; j < 64; ++j) {
    float a = iS1[row0 + j] * h2f(e1P[idx]);
    float cu = iS2[row0 + j] * h2f(e2P[idx]) * h2f(uP[idx]);
    s = fmaf(a, s, cu);
    p *= a;
    idx += H_N;
  }
  cP[gt] = p;
  cS[gt] = s;
}

__global__ void scan_pass3(const unsigned short* __restrict__ e1P,
                           const unsigned short* __restrict__ e2P,
                           const unsigned short* __restrict__ uP,
                           const float* __restrict__ iS1,
                           const float* __restrict__ iS2,
                           const float* __restrict__ cP,
                           const float* __restrict__ cS,
                           float* __restrict__ out) {
  int gt = blockIdx.x * 256 + threadIdx.x;
  int chunk = gt >> 14;
  int r = gt & 16383;
  int b = r >> 9, h = r & 511;
  float s = 0.f;
  for (int c2 = 0; c2 < chunk; ++c2)
    s = fmaf(cP[c2 * 16384 + r], s, cS[c2 * 16384 + r]);
  int row0 = b * T_N + chunk * 64;
  size_t idx = (size_t)row0 * H_N + h;
#pragma unroll 4
  for (int j = 0; j < 64; ++j) {
    float a = iS1[row0 + j] * h2f(e1P[idx]);
    float cu = iS2[row0 + j] * h2f(e2P[idx]) * h2f(uP[idx]);
    s = fmaf(a, s, cu);
    out[idx] = s;
    idx += H_N;
  }
}

extern "C" void kernel_launch(void* const* d_in, const int* in_sizes, int n_in,
                              void* d_out, int out_size, void* d_ws, size_t ws_size,
                              hipStream_t stream) {
  const float* x  = (const float*)d_in[0];
  const float* W0 = (const float*)d_in[1];
  const float* W1 = (const float*)d_in[2];
  const float* W2 = (const float*)d_in[3];
  const float* b0 = (const float*)d_in[4];
  const float* b1 = (const float*)d_in[5];
  const float* b2 = (const float*)d_in[6];
  float* out = (float*)d_out;

  char* ws = (char*)d_ws;
  unsigned short* xb  = (unsigned short*)ws;                  // 16 MB  bf16 x
  unsigned short* Wt  = (unsigned short*)(ws + 16777216);     // 1.5 MB bf16 W^T x3
  unsigned short* uP  = (unsigned short*)(ws + 18350080);     // 16 MB  f16 tanh(u)
  unsigned short* e1P = (unsigned short*)(ws + 35127296);     // 16 MB  f16 exp(z1)
  unsigned short* e2P = (unsigned short*)(ws + 51904512);     // 16 MB  f16 exp(z2)
  float*          S1  = (float*)(ws + 68681728);              // 64 KB  rowsum e1
  float*          S2  = (float*)(ws + 68747264);              // 64 KB  rowsum e2
  float*          cP  = (float*)(ws + 68812800);              // 0.5 MB chunk prod
  float*          cS  = (float*)(ws + 69337088);              // 0.5 MB chunk partial
  // total 69,861,376 bytes

  zero_sums<<<32, 256, 0, stream>>>(S1);   // zeroes S1+S2 (contiguous 128KB)
  prep_kernel<<<2816, 256, 0, stream>>>(x, W0, W1, W2, xb, Wt);
  gemm3<<<dim3(128, 4, 3), 256, 0, stream>>>(xb, Wt, b0, b1, b2,
                                             uP, e1P, e2P, S1, S2);
  inv_sums<<<128, 256, 0, stream>>>(S1);   // inverts S1+S2 in place
  scan_pass1<<<512, 256, 0, stream>>>(e1P, e2P, uP, S1, S2, cP, cS);
  scan_pass3<<<512, 256, 0, stream>>>(e1P, e2P, uP, S1, S2, cP, cS, out);
}

// Round 11
// 90.517 us; speedup vs baseline: 1.0029x; 1.0029x over previous
//
#include <hip/hip_runtime.h>
#include <hip/hip_bf16.h>

#define B_N 32
#define T_N 512
#define D_N 512
#define H_N 512
#define M_N (B_N * T_N)   // 16384

typedef __attribute__((ext_vector_type(8))) short bf16x8;   // generic 16B
typedef __attribute__((ext_vector_type(4))) float f32x4;

__device__ __forceinline__ unsigned short f2bf(float f) {
  unsigned u = __float_as_uint(f);
  u += 0x7FFFu + ((u >> 16) & 1u);   // RTNE
  return (unsigned short)(u >> 16);
}
__device__ __forceinline__ unsigned short f2h(float f) {
  _Float16 h = (_Float16)f;
  return *(unsigned short*)&h;
}
__device__ __forceinline__ float h2f(unsigned short u) {
  _Float16 h = *(_Float16*)&u;
  return (float)h;
}

#define GLOAD16(g, l) __builtin_amdgcn_global_load_lds( \
    (const __attribute__((address_space(1))) void*)(g), \
    (__attribute__((address_space(3))) void*)(l), 16, 0, 0)

// ---------------------------------------------------------------------------
// prep: blocks [0,768) transpose+convert W -> Wt[id][n][k] bf16;
// blocks [768, 2816) convert x f32 -> bf16.
// ---------------------------------------------------------------------------
__global__ void prep_kernel(const float* __restrict__ x,
                            const float* __restrict__ W0,
                            const float* __restrict__ W1,
                            const float* __restrict__ W2,
                            unsigned short* __restrict__ xb,
                            unsigned short* __restrict__ Wt) {
  int blk = blockIdx.x;
  int tid = threadIdx.x;
  if (blk < 768) {
    __shared__ float tile[32][33];
    int id = blk >> 8;
    int t = blk & 255;
    int kr = (t >> 4) << 5;
    int nc = (t & 15) << 5;
    const float* W = (id == 0) ? W0 : (id == 1) ? W1 : W2;
    unsigned short* Wo = Wt + (size_t)id * (D_N * H_N);
    int tx = tid & 31, ty0 = tid >> 5;
    for (int ty = ty0; ty < 32; ty += 8)
      tile[ty][tx] = W[(size_t)(kr + ty) * H_N + nc + tx];
    __syncthreads();
    for (int ty = ty0; ty < 32; ty += 8)
      Wo[(size_t)(nc + ty) * D_N + kr + tx] = f2bf(tile[tx][ty]);
  } else {
    int b = blk - 768;
    const float4* xv = (const float4*)x;
#pragma unroll
    for (int u = 0; u < 4; ++u) {
      int i = b * 1024 + u * 256 + tid;
      float4 v = xv[i];
      ushort4 o;
      o.x = f2bf(v.x); o.y = f2bf(v.y); o.z = f2bf(v.z); o.w = f2bf(v.w);
      ((ushort4*)xb)[i] = o;
    }
  }
}

// zero the atomic row-sum accumulators (runs every call: deterministic)
__global__ void zero_sums(float* __restrict__ S) {
  ((float4*)S)[blockIdx.x * 256 + threadIdx.x] = (float4){0.f, 0.f, 0.f, 0.f};
}

// invert the row sums in place (IEEE divide)
__global__ void inv_sums(float* __restrict__ S) {
  int i = blockIdx.x * 256 + threadIdx.x;   // 0..32767 covers S1+S2
  S[i] = 1.f / S[i];
}

// ---------------------------------------------------------------------------
// gemm3 v10: 128x128 tile, BK=32, 16 K-steps, 4 waves (64x64 quadrants).
// Triple-buffered LDS (3x16KB=48KB) + raw s_barrier + counted vmcnt(4),
// each WB pinned by sched_barrier(0) (v9: fixed the rule-18 race, verified
// absmax 4.88e-4).
// v9 perf lesson: linear 64B rows are ~8-way bank-conflicted on
// ds_read_b128 (bank_start = (16*row+4*g)%32 depends only on row&1,g ->
// 3.1M conflicts, +6us).  v10 re-instates the v3/v5-VERIFIED 64B-row XOR
// swizzle: phys slot = g ^ ((row>>1)&3).  Write side folds the inverse
// into the per-lane GLOBAL source (linear LDS dest, rule 21); both staged
// rows (r, r+64) share the same swizzle since (r+64)>>1 ≡ r>>1 (mod 4).
// Rows 0..7 now map to distinct 4-bank windows; residual 2-way alias is
// free (m136).  Expected conflicts ~260K (v5 measurement).
// ---------------------------------------------------------------------------
__global__ __launch_bounds__(256) void gemm3(
    const unsigned short* __restrict__ xb,
    const unsigned short* __restrict__ Wt,
    const float* __restrict__ bDu,
    const float* __restrict__ bDr1,
    const float* __restrict__ bDr2,
    unsigned short* __restrict__ uP,
    unsigned short* __restrict__ e1P,
    unsigned short* __restrict__ e2P,
    float* __restrict__ S1,
    float* __restrict__ S2) {
  // A bufs @ 0/8192/16384, B bufs @ 24576/32768/40960 (each 128x32 bf16=8KB)
  __shared__ __align__(16) char smem[49152];

  const int tid = threadIdx.x;      // 0..255
  const int lane = tid & 63;
  const int wv = tid >> 6;          // 0..3
  const int wr = wv >> 1;           // wave row (0..1)
  const int wc = wv & 1;            // wave col (0..1)
  const int g = lane >> 4;          // 0..3 (logical 16B k-chunk)
  const int c16 = lane & 15;

  const int m0 = blockIdx.x * 128;
  const int n0 = blockIdx.y * 128;
  const int id = blockIdx.z;
  const unsigned short* Wp = Wt + (size_t)id * (D_N * H_N);

  f32x4 acc[4][4];
#pragma unroll
  for (int mt = 0; mt < 4; ++mt)
#pragma unroll
    for (int nt = 0; nt < 4; ++nt)
      acc[mt][nt] = (f32x4){0.f, 0.f, 0.f, 0.f};

  // staging: chunk c = i*256+tid -> row c>>2, phys slot c&3.
  // phys slot p of row r holds logical chunk p ^ ((r>>1)&3)  (involution)
  const int srow = wv * 16 + (lane >> 2);                       // + i*64
  const int selem = (((lane & 3) ^ ((srow >> 1) & 3))) * 8;     // swizzled src
  const unsigned short* aSrc = xb + (size_t)(m0 + srow) * D_N + selem;
  const unsigned short* bSrc = Wp + (size_t)(n0 + srow) * D_N + selem;
  const int dstOff = wv * 1024;                     // + i*4096 (+lane*16 hw)

  // read side: logical chunk g of row (..+c16) sits at phys slot g^((c16>>1)&3)
  const int sr = (g ^ ((c16 >> 1) & 3)) << 4;

#define STAGE(ab, kstep) do {                                            \
    const int k0_ = (kstep) * 32;                                        \
    GLOAD16(aSrc + k0_,                 smem + (ab) * 8192 + dstOff);    \
    GLOAD16(aSrc + 64 * D_N + k0_,      smem + (ab) * 8192 + dstOff + 4096); \
    GLOAD16(bSrc + k0_,         smem + 24576 + (ab) * 8192 + dstOff);    \
    GLOAD16(bSrc + 64 * D_N + k0_, smem + 24576 + (ab) * 8192 + dstOff + 4096); \
  } while (0)

#define COMPUTE(ab) do {                                                 \
    bf16x8 af[4], bb[4];                                                 \
    _Pragma("unroll")                                                    \
    for (int mt = 0; mt < 4; ++mt)                                       \
      af[mt] = *(const bf16x8*)(smem + (ab) * 8192 +                     \
                                (wr * 64 + mt * 16 + c16) * 64 + sr);    \
    _Pragma("unroll")                                                    \
    for (int nt = 0; nt < 4; ++nt)                                       \
      bb[nt] = *(const bf16x8*)(smem + 24576 + (ab) * 8192 +             \
                                (wc * 64 + nt * 16 + c16) * 64 + sr);    \
    _Pragma("unroll")                                                    \
    for (int mt = 0; mt < 4; ++mt)                                       \
      _Pragma("unroll")                                                  \
      for (int nt = 0; nt < 4; ++nt)                                     \
        acc[mt][nt] = __builtin_amdgcn_mfma_f32_16x16x32_bf16(           \
            af[mt], bb[nt], acc[mt][nt], 0, 0, 0);                       \
  } while (0)

  // wait+barrier pinned with sched_barrier(0) fences (rule-18 hardening)
#define WB(n) do {                                                       \
    __builtin_amdgcn_sched_barrier(0);                                   \
    asm volatile("s_waitcnt vmcnt(" #n ")\n\ts_barrier" ::: "memory");   \
    __builtin_amdgcn_sched_barrier(0);                                   \
  } while (0)

  STAGE(0, 0);
  STAGE(1, 1);
#pragma unroll 1
  for (int i = 0; i < 4; ++i) {      // t = 3i .. 3i+2 ; stages 3i+2 .. 3i+4
    WB(4); STAGE(2, 3 * i + 2); COMPUTE(0);
    WB(4); STAGE(0, 3 * i + 3); COMPUTE(1);
    WB(4); STAGE(1, 3 * i + 4); COMPUTE(2);
  }
  // tail: computes 12..15 (stages 14,15 still to issue)
  WB(4); STAGE(2, 14); COMPUTE(0);   // t=12
  WB(4); STAGE(0, 15); COMPUTE(1);   // t=13
  WB(4); COMPUTE(2);                 // t=14
  WB(0); COMPUTE(0);                 // t=15

  // ---- epilogue (elementwise + fused row-sums) ----
  const float* bp = (id == 0) ? bDu : (id == 1) ? bDr1 : bDr2;
  unsigned short* outp = (id == 0) ? uP : (id == 1) ? e1P : e2P;
  float* Sp = (id == 1) ? S1 : S2;
  float bias[4];
#pragma unroll
  for (int nt = 0; nt < 4; ++nt)
    bias[nt] = bp[n0 + wc * 64 + nt * 16 + c16];

#pragma unroll
  for (int mt = 0; mt < 4; ++mt)
#pragma unroll
    for (int i = 0; i < 4; ++i) {
      int row = m0 + wr * 64 + mt * 16 + g * 4 + i;
      unsigned short* op = outp + (size_t)row * H_N + n0 + wc * 64 + c16;
      if (id == 0) {
#pragma unroll
        for (int nt = 0; nt < 4; ++nt) {
          float z = acc[mt][nt][i] + bias[nt];
          float e = __expf(2.f * z);   // tanh(z) = 1 - 2/(e^{2z}+1)
          op[nt * 16] = f2h(1.f - 2.f * __builtin_amdgcn_rcpf(e + 1.f));
        }
      } else {
        float ps = 0.f;
#pragma unroll
        for (int nt = 0; nt < 4; ++nt) {
          float e = __expf(acc[mt][nt][i] + bias[nt]);
          op[nt * 16] = f2h(e);
          ps += e;
        }
        ps += __shfl_xor(ps, 1);
        ps += __shfl_xor(ps, 2);
        ps += __shfl_xor(ps, 4);
        ps += __shfl_xor(ps, 8);
        if (c16 == 0) atomicAdd(&Sp[row], ps);
      }
    }
#undef STAGE
#undef COMPUTE
#undef WB
}

// ---------------------------------------------------------------------------
// Chunked linear-recurrence scan: s_t = r1_t*s + r2_t*u_t, with
// r_i = e_i * iS_i (iS precomputed IEEE inverse; lane-uniform broadcast).
// ---------------------------------------------------------------------------
__global__ void scan_pass1(const unsigned short* __restrict__ e1P,
                           const unsigned short* __restrict__ e2P,
                           const unsigned short* __restrict__ uP,
                           const float* __restrict__ iS1,
                           const float* __restrict__ iS2,
                           float* __restrict__ cP,
                           float* __restrict__ cS) {
  int gt = blockIdx.x * 256 + threadIdx.x;  // 0..131071
  int chunk = gt >> 14;
  int r = gt & 16383;
  int b = r >> 9, h = r & 511;
  int row0 = b * T_N + chunk * 64;
  size_t idx = (size_t)row0 * H_N + h;
  float p = 1.f, s = 0.f;
#pragma unroll 4
  for (int j = 0; j < 64; ++j) {
    float a = iS1[row0 + j] * h2f(e1P[idx]);
    float cu = iS2[row0 + j] * h2f(e2P[idx]) * h2f(uP[idx]);
    s = fmaf(a, s, cu);
    p *= a;
    idx += H_N;
  }
  cP[gt] = p;
  cS[gt] = s;
}

__global__ void scan_pass3(const unsigned short* __restrict__ e1P,
                           const unsigned short* __restrict__ e2P,
                           const unsigned short* __restrict__ uP,
                           const float* __restrict__ iS1,
                           const float* __restrict__ iS2,
                           const float* __restrict__ cP,
                           const float* __restrict__ cS,
                           float* __restrict__ out) {
  int gt = blockIdx.x * 256 + threadIdx.x;
  int chunk = gt >> 14;
  int r = gt & 16383;
  int b = r >> 9, h = r & 511;
  float s = 0.f;
  for (int c2 = 0; c2 < chunk; ++c2)
    s = fmaf(cP[c2 * 16384 + r], s, cS[c2 * 16384 + r]);
  int row0 = b * T_N + chunk * 64;
  size_t idx = (size_t)row0 * H_N + h;
#pragma unroll 4
  for (int j = 0; j < 64; ++j) {
    float a = iS1[row0 + j] * h2f(e1P[idx]);
    float cu = iS2[row0 + j] * h2f(e2P[idx]) * h2f(uP[idx]);
    s = fmaf(a, s, cu);
    out[idx] = s;
    idx += H_N;
  }
}

extern "C" void kernel_launch(void* const* d_in, const int* in_sizes, int n_in,
                              void* d_out, int out_size, void* d_ws, size_t ws_size,
                              hipStream_t stream) {
  const float* x  = (const float*)d_in[0];
  const float* W0 = (const float*)d_in[1];
  const float* W1 = (const float*)d_in[2];
  const float* W2 = (const float*)d_in[3];
  const float* b0 = (const float*)d_in[4];
  const float* b1 = (const float*)d_in[5];
  const float* b2 = (const float*)d_in[6];
  float* out = (float*)d_out;

  char* ws = (char*)d_ws;
  unsigned short* xb  = (unsigned short*)ws;                  // 16 MB  bf16 x
  unsigned short* Wt  = (unsigned short*)(ws + 16777216);     // 1.5 MB bf16 W^T x3
  unsigned short* uP  = (unsigned short*)(ws + 18350080);     // 16 MB  f16 tanh(u)
  unsigned short* e1P = (unsigned short*)(ws + 35127296);     // 16 MB  f16 exp(z1)
  unsigned short* e2P = (unsigned short*)(ws + 51904512);     // 16 MB  f16 exp(z2)
  float*          S1  = (float*)(ws + 68681728);              // 64 KB  rowsum e1
  float*          S2  = (float*)(ws + 68747264);              // 64 KB  rowsum e2
  float*          cP  = (float*)(ws + 68812800);              // 0.5 MB chunk prod
  float*          cS  = (float*)(ws + 69337088);              // 0.5 MB chunk partial
  // total 69,861,376 bytes

  zero_sums<<<32, 256, 0, stream>>>(S1);   // zeroes S1+S2 (contiguous 128KB)
  prep_kernel<<<2816, 256, 0, stream>>>(x, W0, W1, W2, xb, Wt);
  gemm3<<<dim3(128, 4, 3), 256, 0, stream>>>(xb, Wt, b0, b1, b2,
                                             uP, e1P, e2P, S1, S2);
  inv_sums<<<128, 256, 0, stream>>>(S1);   // inverts S1+S2 in place
  scan_pass1<<<512, 256, 0, stream>>>(e1P, e2P, uP, S1, S2, cP, cS);
  scan_pass3<<<512, 256, 0, stream>>>(e1P, e2P, uP, S1, S2, cP, cS, out);
}

// Round 12
// 79.873 us; speedup vs baseline: 1.1365x; 1.1333x over previous
//
#include <hip/hip_runtime.h>
#include <hip/hip_bf16.h>

#define B_N 32
#define T_N 512
#define D_N 512
#define H_N 512
#define M_N (B_N * T_N)   // 16384

typedef __attribute__((ext_vector_type(8))) short bf16x8;   // generic 16B
typedef __attribute__((ext_vector_type(4))) float f32x4;

__device__ __forceinline__ unsigned short f2bf(float f) {
  unsigned u = __float_as_uint(f);
  u += 0x7FFFu + ((u >> 16) & 1u);   // RTNE
  return (unsigned short)(u >> 16);
}
__device__ __forceinline__ unsigned short f2h(float f) {
  _Float16 h = (_Float16)f;
  return *(unsigned short*)&h;
}
__device__ __forceinline__ float h2f(unsigned short u) {
  _Float16 h = *(_Float16*)&u;
  return (float)h;
}

#define GLOAD16(g, l) __builtin_amdgcn_global_load_lds( \
    (const __attribute__((address_space(1))) void*)(g), \
    (__attribute__((address_space(3))) void*)(l), 16, 0, 0)

// ---------------------------------------------------------------------------
// prep: blocks [0,768) transpose+convert W -> Wt[id][n][k] bf16;
// blocks [768,2816) convert x f32 -> bf16; blocks [2816,2848) zero S1/S2.
// ---------------------------------------------------------------------------
__global__ void prep_kernel(const float* __restrict__ x,
                            const float* __restrict__ W0,
                            const float* __restrict__ W1,
                            const float* __restrict__ W2,
                            unsigned short* __restrict__ xb,
                            unsigned short* __restrict__ Wt,
                            float* __restrict__ S) {
  int blk = blockIdx.x;
  int tid = threadIdx.x;
  if (blk < 768) {
    __shared__ float tile[32][33];
    int id = blk >> 8;
    int t = blk & 255;
    int kr = (t >> 4) << 5;
    int nc = (t & 15) << 5;
    const float* W = (id == 0) ? W0 : (id == 1) ? W1 : W2;
    unsigned short* Wo = Wt + (size_t)id * (D_N * H_N);
    int tx = tid & 31, ty0 = tid >> 5;
    for (int ty = ty0; ty < 32; ty += 8)
      tile[ty][tx] = W[(size_t)(kr + ty) * H_N + nc + tx];
    __syncthreads();
    for (int ty = ty0; ty < 32; ty += 8)
      Wo[(size_t)(nc + ty) * D_N + kr + tx] = f2bf(tile[tx][ty]);
  } else if (blk < 2816) {
    int b = blk - 768;
    const float4* xv = (const float4*)x;
#pragma unroll
    for (int u = 0; u < 4; ++u) {
      int i = b * 1024 + u * 256 + tid;
      float4 v = xv[i];
      ushort4 o;
      o.x = f2bf(v.x); o.y = f2bf(v.y); o.z = f2bf(v.z); o.w = f2bf(v.w);
      ((ushort4*)xb)[i] = o;
    }
  } else {
    // zero S1+S2 (contiguous 128KB = 32768 floats = 8192 float4)
    ((float4*)S)[(blk - 2816) * 256 + tid] = (float4){0.f, 0.f, 0.f, 0.f};
  }
}

// ---------------------------------------------------------------------------
// gemm3 v11: 128x128 tile, BK=64, 8 K-steps, 4 waves (64x64 quadrants).
// Double-buffered LDS (2x(16+16)KB = 64KB -> 2 blocks/CU) with TRUE counted
// waits: v7's vmcnt(8) sat before __syncthreads, which re-drains to 0 --
// the counted pipeline never engaged.  v11 uses raw barriers throughout:
//   WB(8): s_waitcnt vmcnt(8); s_barrier   (stage t landed; t+1 in flight)
//   SB   : s_barrier                       (all waves done reading buf
//                                           before STAGE overwrites it)
// both pinned by sched_barrier(0) (v9 rule-18 hardening, verified correct).
// Ledger: entering step t outstanding = {t,t+1} = 16 loads; WB(8) drains
// exactly stage t; never 0 mid-loop (T4).  STAGE(buf,t+2) only after SB --
// the v8 overwrite race is structurally excluded.
// Swizzle (v1/v7-verified, 128B rows): phys 16B slot = s ^ (row&7);
// inverse folded into per-lane GLOBAL source (linear LDS dest, rule 21).
// Epilogue: tanh/exp f16 + fused per-row exp-sums (shfl + atomicAdd),
// verified v10 (absmax 4.88e-4).
// ---------------------------------------------------------------------------
__global__ __launch_bounds__(256) void gemm3(
    const unsigned short* __restrict__ xb,
    const unsigned short* __restrict__ Wt,
    const float* __restrict__ bDu,
    const float* __restrict__ bDr1,
    const float* __restrict__ bDr2,
    unsigned short* __restrict__ uP,
    unsigned short* __restrict__ e1P,
    unsigned short* __restrict__ e2P,
    float* __restrict__ S1,
    float* __restrict__ S2) {
  // A0 @0, A1 @16384, B0 @32768, B1 @49152 (each 128x64 bf16 = 16KB)
  __shared__ __align__(16) char smem[65536];

  const int tid = threadIdx.x;      // 0..255
  const int lane = tid & 63;
  const int wv = tid >> 6;          // 0..3
  const int wr = wv >> 1;           // wave row (0..1)
  const int wc = wv & 1;            // wave col (0..1)
  const int g = lane >> 4;          // 0..3
  const int c16 = lane & 15;

  const int m0 = blockIdx.x * 128;
  const int n0 = blockIdx.y * 128;
  const int id = blockIdx.z;
  const unsigned short* Wp = Wt + (size_t)id * (D_N * H_N);

  f32x4 acc[4][4];
#pragma unroll
  for (int mt = 0; mt < 4; ++mt)
#pragma unroll
    for (int nt = 0; nt < 4; ++nt)
      acc[mt][nt] = (f32x4){0.f, 0.f, 0.f, 0.f};

  // staging: 1024 16B-chunks/tile; thread -> chunks i*256+tid.
  // row = i*32 + (tid>>3); phys slot = tid&7; logical = phys ^ (row&7)
  const int rowoff = tid >> 3;                         // 0..31
  const int lsl = ((tid & 7) ^ ((tid >> 3) & 7)) * 8;  // swizzled src (elems)
  const unsigned short* aSrc = xb + (size_t)(m0 + rowoff) * D_N + lsl;
  const unsigned short* bSrc = Wp + (size_t)(n0 + rowoff) * D_N + lsl;
  const int dstOff = wv * 1024;   // wave-uniform LDS dest part (+lane*16 hw)

  // read-side: logical chunk (kh*4+g) of row r sits at phys slot ^(r&7)
  const int h3 = c16 & 7;

#define STAGE(buf, kstep) do {                                           \
    const int k0_ = (kstep) * 64;                                        \
    _Pragma("unroll")                                                    \
    for (int i = 0; i < 4; ++i)                                          \
      GLOAD16(aSrc + (size_t)i * (32 * D_N) + k0_,                       \
              smem + (buf) * 16384 + dstOff + i * 4096);                 \
    _Pragma("unroll")                                                    \
    for (int i = 0; i < 4; ++i)                                          \
      GLOAD16(bSrc + (size_t)i * (32 * D_N) + k0_,                       \
              smem + 32768 + (buf) * 16384 + dstOff + i * 4096);         \
  } while (0)

#define COMPUTE(buf) do {                                                \
    _Pragma("unroll")                                                    \
    for (int kh = 0; kh < 2; ++kh) {                                     \
      const int soff = ((kh * 4 + g) ^ h3) << 4;                         \
      bf16x8 af[4], bb[4];                                               \
      _Pragma("unroll")                                                  \
      for (int mt = 0; mt < 4; ++mt)                                     \
        af[mt] = *(const bf16x8*)(smem + (buf) * 16384 +                 \
                                  (wr * 64 + mt * 16 + c16) * 128 + soff); \
      _Pragma("unroll")                                                  \
      for (int nt = 0; nt < 4; ++nt)                                     \
        bb[nt] = *(const bf16x8*)(smem + 32768 + (buf) * 16384 +         \
                                  (wc * 64 + nt * 16 + c16) * 128 + soff); \
      _Pragma("unroll")                                                  \
      for (int mt = 0; mt < 4; ++mt)                                     \
        _Pragma("unroll")                                                \
        for (int nt = 0; nt < 4; ++nt)                                   \
          acc[mt][nt] = __builtin_amdgcn_mfma_f32_16x16x32_bf16(         \
              af[mt], bb[nt], acc[mt][nt], 0, 0, 0);                     \
    }                                                                    \
  } while (0)

#define WB(n) do {                                                       \
    __builtin_amdgcn_sched_barrier(0);                                   \
    asm volatile("s_waitcnt vmcnt(" #n ")\n\ts_barrier" ::: "memory");   \
    __builtin_amdgcn_sched_barrier(0);                                   \
  } while (0)

#define SB do {                                                          \
    __builtin_amdgcn_sched_barrier(0);                                   \
    asm volatile("s_barrier" ::: "memory");                              \
    __builtin_amdgcn_sched_barrier(0);                                   \
  } while (0)

  STAGE(0, 0);
  STAGE(1, 1);
#pragma unroll 1
  for (int t = 0; t < 6; ++t) {      // steps 0..5: stage t+2 after SB
    WB(8);                            // stage t landed (t+1 stays in flight)
    COMPUTE(t & 1);
    SB;                               // all waves done reading buf (t&1)
    STAGE(t & 1, t + 2);
  }
  WB(8);  COMPUTE(0);                 // t=6 (outstanding {6,7} -> drains 6)
  WB(0);  COMPUTE(1);                 // t=7

  // ---- epilogue (elementwise + fused row-sums) ----
  const float* bp = (id == 0) ? bDu : (id == 1) ? bDr1 : bDr2;
  unsigned short* outp = (id == 0) ? uP : (id == 1) ? e1P : e2P;
  float* Sp = (id == 1) ? S1 : S2;
  float bias[4];
#pragma unroll
  for (int nt = 0; nt < 4; ++nt)
    bias[nt] = bp[n0 + wc * 64 + nt * 16 + c16];

#pragma unroll
  for (int mt = 0; mt < 4; ++mt)
#pragma unroll
    for (int i = 0; i < 4; ++i) {
      int row = m0 + wr * 64 + mt * 16 + g * 4 + i;
      unsigned short* op = outp + (size_t)row * H_N + n0 + wc * 64 + c16;
      if (id == 0) {
#pragma unroll
        for (int nt = 0; nt < 4; ++nt) {
          float z = acc[mt][nt][i] + bias[nt];
          float e = __expf(2.f * z);   // tanh(z) = 1 - 2/(e^{2z}+1)
          op[nt * 16] = f2h(1.f - 2.f * __builtin_amdgcn_rcpf(e + 1.f));
        }
      } else {
        float ps = 0.f;
#pragma unroll
        for (int nt = 0; nt < 4; ++nt) {
          float e = __expf(acc[mt][nt][i] + bias[nt]);
          op[nt * 16] = f2h(e);
          ps += e;
        }
        ps += __shfl_xor(ps, 1);
        ps += __shfl_xor(ps, 2);
        ps += __shfl_xor(ps, 4);
        ps += __shfl_xor(ps, 8);
        if (c16 == 0) atomicAdd(&Sp[row], ps);
      }
    }
#undef STAGE
#undef COMPUTE
#undef WB
#undef SB
}

// ---------------------------------------------------------------------------
// Chunked linear-recurrence scan.  Per block, (b,chunk) are uniform -> the
// 64 row-sums are preloaded into LDS with in-block inversion (64 IEEE
// divides per array per block, replacing the inv_sums kernel and 64
// redundant VMEM loads per thread).
// ---------------------------------------------------------------------------
__global__ void scan_pass1(const unsigned short* __restrict__ e1P,
                           const unsigned short* __restrict__ e2P,
                           const unsigned short* __restrict__ uP,
                           const float* __restrict__ S1,
                           const float* __restrict__ S2,
                           float* __restrict__ cP,
                           float* __restrict__ cS) {
  __shared__ float ls1[64], ls2[64];
  int gt = blockIdx.x * 256 + threadIdx.x;  // 0..131071
  int chunk = gt >> 14;
  int r = gt & 16383;
  int b = r >> 9, h = r & 511;
  int row0 = b * T_N + chunk * 64;          // block-uniform
  if (threadIdx.x < 64) ls1[threadIdx.x] = 1.f / S1[row0 + threadIdx.x];
  else if (threadIdx.x < 128) ls2[threadIdx.x - 64] = 1.f / S2[row0 + threadIdx.x - 64];
  __syncthreads();
  size_t idx = (size_t)row0 * H_N + h;
  float p = 1.f, s = 0.f;
#pragma unroll 4
  for (int j = 0; j < 64; ++j) {
    float a = ls1[j] * h2f(e1P[idx]);
    float cu = ls2[j] * h2f(e2P[idx]) * h2f(uP[idx]);
    s = fmaf(a, s, cu);
    p *= a;
    idx += H_N;
  }
  cP[gt] = p;
  cS[gt] = s;
}

__global__ void scan_pass3(const unsigned short* __restrict__ e1P,
                           const unsigned short* __restrict__ e2P,
                           const unsigned short* __restrict__ uP,
                           const float* __restrict__ S1,
                           const float* __restrict__ S2,
                           const float* __restrict__ cP,
                           const float* __restrict__ cS,
                           float* __restrict__ out) {
  __shared__ float ls1[64], ls2[64];
  int gt = blockIdx.x * 256 + threadIdx.x;
  int chunk = gt >> 14;
  int r = gt & 16383;
  int b = r >> 9, h = r & 511;
  int row0 = b * T_N + chunk * 64;
  if (threadIdx.x < 64) ls1[threadIdx.x] = 1.f / S1[row0 + threadIdx.x];
  else if (threadIdx.x < 128) ls2[threadIdx.x - 64] = 1.f / S2[row0 + threadIdx.x - 64];
  float s = 0.f;
  for (int c2 = 0; c2 < chunk; ++c2)
    s = fmaf(cP[c2 * 16384 + r], s, cS[c2 * 16384 + r]);
  __syncthreads();
  size_t idx = (size_t)row0 * H_N + h;
#pragma unroll 4
  for (int j = 0; j < 64; ++j) {
    float a = ls1[j] * h2f(e1P[idx]);
    float cu = ls2[j] * h2f(e2P[idx]) * h2f(uP[idx]);
    s = fmaf(a, s, cu);
    out[idx] = s;
    idx += H_N;
  }
}

extern "C" void kernel_launch(void* const* d_in, const int* in_sizes, int n_in,
                              void* d_out, int out_size, void* d_ws, size_t ws_size,
                              hipStream_t stream) {
  const float* x  = (const float*)d_in[0];
  const float* W0 = (const float*)d_in[1];
  const float* W1 = (const float*)d_in[2];
  const float* W2 = (const float*)d_in[3];
  const float* b0 = (const float*)d_in[4];
  const float* b1 = (const float*)d_in[5];
  const float* b2 = (const float*)d_in[6];
  float* out = (float*)d_out;

  char* ws = (char*)d_ws;
  unsigned short* xb  = (unsigned short*)ws;                  // 16 MB  bf16 x
  unsigned short* Wt  = (unsigned short*)(ws + 16777216);     // 1.5 MB bf16 W^T x3
  unsigned short* uP  = (unsigned short*)(ws + 18350080);     // 16 MB  f16 tanh(u)
  unsigned short* e1P = (unsigned short*)(ws + 35127296);     // 16 MB  f16 exp(z1)
  unsigned short* e2P = (unsigned short*)(ws + 51904512);     // 16 MB  f16 exp(z2)
  float*          S1  = (float*)(ws + 68681728);              // 64 KB  rowsum e1
  float*          S2  = (float*)(ws + 68747264);              // 64 KB  rowsum e2
  float*          cP  = (float*)(ws + 68812800);              // 0.5 MB chunk prod
  float*          cS  = (float*)(ws + 69337088);              // 0.5 MB chunk partial
  // total 69,861,376 bytes

  prep_kernel<<<2848, 256, 0, stream>>>(x, W0, W1, W2, xb, Wt, S1);
  gemm3<<<dim3(128, 4, 3), 256, 0, stream>>>(xb, Wt, b0, b1, b2,
                                             uP, e1P, e2P, S1, S2);
  scan_pass1<<<512, 256, 0, stream>>>(e1P, e2P, uP, S1, S2, cP, cS);
  scan_pass3<<<512, 256, 0, stream>>>(e1P, e2P, uP, S1, S2, cP, cS, out);
}